// Round 13
// baseline (175.805 us; speedup 1.0000x reference)
//
#include <hip/hip_runtime.h>
#include <math.h>

#define BB 2
#define II 128
#define JJ 512
#define CC 256
#define NEL (BB*II*JJ)   // 131072
#define NINF (-INFINITY)
#define K10 4.5399929762484854e-5f   // exp(-10)

typedef float f32x4 __attribute__((ext_vector_type(4)));   // asm-operand-safe vec4

// ---------------- DPP wave64 primitives ----------------
template<int CTRL, int RM = 0xf, int BM = 0xf, bool BC = true>
__device__ __forceinline__ float dppf(float x) {
    return __int_as_float(__builtin_amdgcn_update_dpp(
        0, __float_as_int(x), CTRL, RM, BM, BC));
}
__device__ __forceinline__ float wscan_incl(float x) {
    x += dppf<0x111>(x);              // row_shr:1
    x += dppf<0x112>(x);              // row_shr:2
    x += dppf<0x114>(x);              // row_shr:4
    x += dppf<0x118>(x);              // row_shr:8
    x += dppf<0x142, 0xa>(x);         // row_bcast:15 -> rows 1,3
    x += dppf<0x143, 0xc>(x);         // row_bcast:31 -> rows 2,3
    return x;
}
__device__ __forceinline__ float lane_shr1(float x) { return dppf<0x138>(x); }
__device__ __forceinline__ float bcast63(float x) {
    return __int_as_float(__builtin_amdgcn_readlane(__float_as_int(x), 63));
}

// in-lane inclusive prefix sum, tree form (depth 3)
__device__ __forceinline__ void tree_prefix8(const float x[8], float P[8]) {
    float t[8];
    t[0] = x[0];
    #pragma unroll
    for (int q = 1; q < 8; ++q) t[q] = x[q] + x[q-1];
    float u[8];
    u[0] = t[0]; u[1] = t[1];
    #pragma unroll
    for (int q = 2; q < 8; ++q) u[q] = t[q] + t[q-2];
    P[0] = u[0]; P[1] = u[1]; P[2] = u[2]; P[3] = u[3];
    #pragma unroll
    for (int q = 4; q < 8; ++q) P[q] = u[q] + u[q-4];
}

__device__ __forceinline__ void loadrow8(const float* p, float v[8]) {
    float4 a = *reinterpret_cast<const float4*>(p);
    float4 b = *reinterpret_cast<const float4*>(p + 4);
    v[0]=a.x; v[1]=a.y; v[2]=a.z; v[3]=a.w;
    v[4]=b.x; v[5]=b.y; v[6]=b.z; v[7]=b.w;
}
__device__ __forceinline__ void storerow8(float* __restrict__ p, const float v[8]) {
    *reinterpret_cast<float4*>(p)     = make_float4(v[0],v[1],v[2],v[3]);
    *reinterpret_cast<float4*>(p + 4) = make_float4(v[4],v[5],v[6],v[7]);
}

// ---------------- hand-held vmem ops (invisible to SIInsertWaitcnts) ----------------
__device__ __forceinline__ void aload2(f32x4 &d0, f32x4 &d1, const float* p) {
    asm volatile("global_load_dwordx4 %0, %2, off\n\t"
                 "global_load_dwordx4 %1, %2, off offset:16"
                 : "=&v"(d0), "=&v"(d1) : "v"(p) : "memory");
}
__device__ __forceinline__ void astore2(f32x4 d0, f32x4 d1, float* p) {
    asm volatile("global_store_dwordx4 %2, %0, off\n\t"
                 "global_store_dwordx4 %2, %1, off offset:16"
                 :: "v"(d0), "v"(d1), "v"(p) : "memory");
}
template<int N> __device__ __forceinline__ void waitcnt_vm() {
    asm volatile("s_waitcnt vmcnt(%0)" :: "i"(N) : "memory");
}

struct Buf { f32x4 e0, e1, w0, w1; };   // one (Ee,W) row fragment: 16 VGPRs

// ================= fused energy + dscan =================
// Grid (BB, II/8), 256 threads. Each block computes 8 FULL rows of e into LDS
// (j-tile loop inside the block; same mel/text tiling as the old energy kernel),
// then runs dscan's per-row math from LDS: e never touches global memory.
// Saves: dscan launch, 1MB e-write + 1MB e-read.
__global__ __launch_bounds__(256) void energy_dscan_kernel(
        const float* __restrict__ text, const float* __restrict__ mel,
        const float* __restrict__ noise, const float* __restrict__ ratio,
        float* __restrict__ Ee, float* __restrict__ Wa, float* __restrict__ Wb) {
    __shared__ float melS[64][65];
    __shared__ float texS[8][65];
    __shared__ float eL[8][JJ];      // 16KB: 8 complete e rows
    int b  = blockIdx.x;
    int i0 = blockIdx.y * 8;
    int t = threadIdx.x;
    int jj = t & 63, ig = t >> 6;
    float temp = 0.1f + 0.9f * ratio[0];
    float rtmp = 1.0f / temp;

    for (int jt = 0; jt < 8; ++jt) {
        int j0 = jt * 64;
        float acc0 = 0.f, acc1 = 0.f;
        for (int cc = 0; cc < CC; cc += 64) {
            #pragma unroll
            for (int k = 0; k < 4; ++k) {
                int idx = t + k * 256;
                int row = idx >> 4, seg = idx & 15;
                float4 v = *reinterpret_cast<const float4*>(
                    mel + (size_t)(b * JJ + j0 + row) * CC + cc + seg * 4);
                melS[row][seg*4+0] = v.x; melS[row][seg*4+1] = v.y;
                melS[row][seg*4+2] = v.z; melS[row][seg*4+3] = v.w;
            }
            if (t < 128) {
                int row = t >> 4, seg = t & 15;
                float4 v = *reinterpret_cast<const float4*>(
                    text + (size_t)(b * II + i0 + row) * CC + cc + seg * 4);
                texS[row][seg*4+0] = v.x; texS[row][seg*4+1] = v.y;
                texS[row][seg*4+2] = v.z; texS[row][seg*4+3] = v.w;
            }
            __syncthreads();
            #pragma unroll 8
            for (int c = 0; c < 64; ++c) {
                float m = melS[jj][c];
                acc0 = fmaf(m, texS[ig*2+0][c], acc0);
                acc1 = fmaf(m, texS[ig*2+1][c], acc1);
            }
            __syncthreads();
        }
        int r0 = (b * II + i0 + ig*2 + 0) * JJ + j0 + jj;
        int r1 = (b * II + i0 + ig*2 + 1) * JJ + j0 + jj;
        eL[ig*2+0][j0 + jj] = (acc0 * (1.0f/256.0f) + noise[r0]) * rtmp;
        eL[ig*2+1][j0 + jj] = (acc1 * (1.0f/256.0f) + noise[r1]) * rtmp;
    }
    __syncthreads();

    // dscan phase: wave w handles local rows 2w, 2w+1 (dscan math verbatim)
    int lane = t & 63;
    int w = t >> 6;
    #pragma unroll
    for (int r = 0; r < 2; ++r) {
        int row = 2 * w + r;
        size_t grow = (size_t)(b * II + i0 + row) * JJ;
        float v[8];
        #pragma unroll
        for (int q = 0; q < 8; ++q) v[q] = eL[row][lane * 8 + q];
        float m = v[0];
        #pragma unroll
        for (int q = 1; q < 8; ++q) m = fmaxf(m, v[q]);
        #pragma unroll
        for (int d = 1; d < 64; d <<= 1) m = fmaxf(m, __shfl_xor(m, d, 64));
        float x[8];
        #pragma unroll
        for (int q = 0; q < 8; ++q) x[q] = __expf(v[q] - m);
        storerow8(Ee + grow + lane * 8, x);
        float run = 0.f, P[8];
        #pragma unroll
        for (int q = 0; q < 8; ++q) { run += x[q]; P[q] = run; }
        float sc = wscan_incl(run);
        float cp = lane_shr1(sc);
        float run2 = 0.f, S[8];
        #pragma unroll
        for (int q = 7; q >= 0; --q) { run2 += x[q]; S[q] = run2; }
        float sd = run2;
        #pragma unroll
        for (int d = 1; d < 64; d <<= 1) { float o = __shfl_down(sd, d, 64); sd += (lane + d < 64) ? o : 0.0f; }
        float cs = __shfl_down(sd, 1, 64); if (lane == 63) cs = 0.f;
        float wa[8], wb[8];
        #pragma unroll
        for (int q = 0; q < 8; ++q) {
            wa[q] = 1.0f / (S[q] + cs);
            wb[q] = 1.0f / (P[q] + cp);
        }
        storerow8(Wa + grow + lane * 8, wa);
        storerow8(Wb + grow + lane * 8, wb);
    }
}

// ======================= scan_ab: all-asm vmem, reg-resident prefetch d=3 =======================
// Byte-identical to the R7 version (best measured total, 129.8us).
// Per step, vmem (all inline asm, exact order): [2 stores][4 loads][wait vmcnt(VM)].
// Steady VM=18; warm-up 14/16; drain 14/10/6. ca/cb accumulate in LDS.
// __launch_bounds__(64,1): prevents the 64-VGPR occupancy cap + scratch spills.

template<bool NORM, int VM, bool PF>
__device__ __forceinline__ void astep(
    int i, int lane, int off,
    const float (&pin)[8], float (&pout)[8], float& c,
    Buf& C, Buf& L,
    const float* __restrict__ EeB, const float* __restrict__ WaB,
    float* __restrict__ paB, float* ldsC)
{
    {
        f32x4 s0 = {pin[0], pin[1], pin[2], pin[3]};
        f32x4 s1 = {pin[4], pin[5], pin[6], pin[7]};
        astore2(s0, s1, paB + (size_t)(i - 1) * JJ + off);   // pin holds row i-1
    }
    if (lane == 0) ldsC[i - 1] = c;
    if (PF) {
        aload2(L.e0, L.e1, EeB + (size_t)(i + 3) * JJ + off);
        aload2(L.w0, L.w1, WaB + (size_t)(i + 3) * JJ + off);
    }
    waitcnt_vm<VM>();
    __builtin_amdgcn_sched_barrier(0);   // rule #18: keep consumers behind the wait
    float CE[8] = {C.e0[0],C.e0[1],C.e0[2],C.e0[3],C.e1[0],C.e1[1],C.e1[2],C.e1[3]};
    float CW[8] = {C.w0[0],C.w0[1],C.w0[2],C.w0[3],C.w1[0],C.w1[1],C.w1[2],C.w1[3]};

    float pup = lane_shr1(pin[7]);
    float y[8];
    y[0] = pup * CW[0];
    #pragma unroll
    for (int q = 1; q < 8; ++q) y[q] = pin[q-1] * CW[q];
    float zz[8];
    #pragma unroll
    for (int q = 0; q < 7; ++q) zz[q] = pin[q];
    zz[7] = (lane == 63) ? 0.0f : pin[7];
    float Y[8], Z[8];
    tree_prefix8(y, Y);
    tree_prefix8(zz, Z);
    float sy = wscan_incl(Y[7]);
    float sz = wscan_incl(Z[7]);
    float oy = lane_shr1(sy);
    float oz = lane_shr1(sz);
    float T  = bcast63(sz);
    #pragma unroll
    for (int q = 0; q < 8; ++q) {
        float S1 = oy + Y[q];                              // incl prefix of y
        float S2 = fmaxf(T - (oz + Z[q]) + zz[q], 0.0f);   // incl suffix of z
        pout[q] = fmaf(CE[q], S1, K10 * S2);
    }
    if (NORM) {
        float Tc = fmaxf(T, 1e-30f);
        float rT = __builtin_amdgcn_rcpf(Tc);
        c += __logf(Tc);
        #pragma unroll
        for (int q = 0; q < 8; ++q) pout[q] *= rT;
    }
}

template<bool NORM, int VM, bool PF>
__device__ __forceinline__ void bstep(
    int i, int lane, int off,
    const float (&pin)[8], float (&pout)[8], float& c,
    Buf& C, Buf& L,
    const float* __restrict__ EeB, const float* __restrict__ WbB,
    float* __restrict__ pbB, float* ldsC)
{
    {
        f32x4 s0 = {pin[0], pin[1], pin[2], pin[3]};
        f32x4 s1 = {pin[4], pin[5], pin[6], pin[7]};
        astore2(s0, s1, pbB + (size_t)(i + 1) * JJ + off);   // pin holds row i+1
    }
    if (lane == 0) ldsC[i + 1] = c;
    if (PF) {
        aload2(L.e0, L.e1, EeB + (size_t)(i - 3) * JJ + 504 - 8 * lane);
        aload2(L.w0, L.w1, WbB + (size_t)(i - 3) * JJ + 504 - 8 * lane);
    }
    waitcnt_vm<VM>();
    __builtin_amdgcn_sched_barrier(0);
    // reversed: CE[q] = rowdata[7-q]  (rowdata[k] = row[504-8*lane+k])
    float CE[8] = {C.e1[3],C.e1[2],C.e1[1],C.e1[0],C.e0[3],C.e0[2],C.e0[1],C.e0[0]};
    float CW[8] = {C.w1[3],C.w1[2],C.w1[1],C.w1[0],C.w0[3],C.w0[2],C.w0[1],C.w0[0]};

    float pup = lane_shr1(pin[7]);
    float pn[8];
    pn[0] = pup;
    #pragma unroll
    for (int q = 1; q < 8; ++q) pn[q] = pin[q-1];
    float w[8];
    #pragma unroll
    for (int q = 0; q < 8; ++q) w[q] = pn[q] * CW[q];
    float W[8], N[8];
    tree_prefix8(w, W);
    tree_prefix8(pn, N);
    float sw = wscan_incl(W[7]);
    float sn = wscan_incl(N[7]);
    float ow = lane_shr1(sw);
    float on = lane_shr1(sn);
    float T  = bcast63(sn);
    #pragma unroll
    for (int q = 0; q < 8; ++q) {
        float QA = ow + W[q];                    // incl prefix of w
        float QB = fmaxf(T - (on + N[q]), 0.0f); // excl suffix of pn
        pout[q] = fmaf(CE[q], QA, K10 * QB);
    }
    if (NORM) {
        float Tc = fmaxf(T, 1e-30f);
        float rT = __builtin_amdgcn_rcpf(Tc);
        c += __logf(Tc);
        #pragma unroll
        for (int q = 0; q < 8; ++q) pout[q] *= rT;
    }
}

__global__ __launch_bounds__(64, 1) void scan_ab_kernel(
        const float* __restrict__ Ee, const float* __restrict__ Wa,
        const float* __restrict__ Wb,
        float* __restrict__ pa, float* __restrict__ pb,
        float* __restrict__ ca, float* __restrict__ cb) {
    __shared__ float ldsC[II];
    int b = blockIdx.x >> 1, dir = blockIdx.x & 1;
    int lane = threadIdx.x, off = lane * 8;
    size_t base = (size_t)b * II * JJ;
    float P0[8], P1[8], P2[8], P3[8], c = 0.0f;
    Buf B0, B1, B2, B3;

    if (dir == 0) {
        const float* EeB = Ee + base; const float* WaB = Wa + base;
        float* paB = pa + base; float* caB = ca + b * II;
        // row 0 via compiler loads (their auto-waits stay ABOVE our asm stream)
        float e0r[8];
        loadrow8(EeB + off, e0r);
        float wa00 = WaB[0];
        #pragma unroll
        for (int q = 0; q < 8; ++q) P0[q] = e0r[q] * wa00;   // row 0
        __builtin_amdgcn_sched_barrier(0);
        // asm prefetch rows 1,2,3 -> B1,B2,B3 (12 vmem ops in flight)
        aload2(B1.e0, B1.e1, EeB + (size_t)1*JJ + off); aload2(B1.w0, B1.w1, WaB + (size_t)1*JJ + off);
        aload2(B2.e0, B2.e1, EeB + (size_t)2*JJ + off); aload2(B2.w0, B2.w1, WaB + (size_t)2*JJ + off);
        aload2(B3.e0, B3.e1, EeB + (size_t)3*JJ + off); aload2(B3.w0, B3.w1, WaB + (size_t)3*JJ + off);
        // warm-up (exact counts)
        astep<true ,14,true>(1, lane, off, P0, P1, c, B1, B0, EeB, WaB, paB, ldsC);
        astep<false,16,true>(2, lane, off, P1, P2, c, B2, B1, EeB, WaB, paB, ldsC);
        #pragma unroll 1
        for (int d = 0; d < 15; ++d) {        // steps 3..122
            int ib = 3 + 8 * d;
            astep<false,18,true>(ib+0, lane, off, P2, P3, c, B3, B2, EeB, WaB, paB, ldsC);
            astep<false,18,true>(ib+1, lane, off, P3, P0, c, B0, B3, EeB, WaB, paB, ldsC);
            astep<true ,18,true>(ib+2, lane, off, P0, P1, c, B1, B0, EeB, WaB, paB, ldsC);
            astep<false,18,true>(ib+3, lane, off, P1, P2, c, B2, B1, EeB, WaB, paB, ldsC);
            astep<false,18,true>(ib+4, lane, off, P2, P3, c, B3, B2, EeB, WaB, paB, ldsC);
            astep<false,18,true>(ib+5, lane, off, P3, P0, c, B0, B3, EeB, WaB, paB, ldsC);
            astep<true ,18,true>(ib+6, lane, off, P0, P1, c, B1, B0, EeB, WaB, paB, ldsC);
            astep<false,18,true>(ib+7, lane, off, P1, P2, c, B2, B1, EeB, WaB, paB, ldsC);
        }
        astep<false,18,true >(123, lane, off, P2, P3, c, B3, B2, EeB, WaB, paB, ldsC);
        astep<false,18,true >(124, lane, off, P3, P0, c, B0, B3, EeB, WaB, paB, ldsC);
        astep<true ,14,false>(125, lane, off, P0, P1, c, B1, B0, EeB, WaB, paB, ldsC);
        astep<false,10,false>(126, lane, off, P1, P2, c, B2, B1, EeB, WaB, paB, ldsC);
        astep<false, 6,false>(127, lane, off, P2, P3, c, B3, B2, EeB, WaB, paB, ldsC);
        storerow8(paB + (size_t)127 * JJ + off, P3);
        if (lane == 0) ldsC[127] = c;
        waitcnt_vm<0>();                       // drain our asm stores before endpgm
        caB[lane]      = ldsC[lane];
        caB[lane + 64] = ldsC[lane + 64];
    } else {
        const float* EeB = Ee + base; const float* WbB = Wb + base;
        float* pbB = pb + base; float* cbB = cb + b * II;
        #pragma unroll
        for (int q = 0; q < 8; ++q) P3[q] = 0.0f;
        P3[0] = (lane == 0) ? 1.0f : 0.0f;   // row 127 (j'=0 <-> orig j=J-1)
        // asm prefetch rows 126,125,124 -> B2,B1,B0 (reversed addressing)
        aload2(B2.e0, B2.e1, EeB + (size_t)126*JJ + 504 - 8*lane); aload2(B2.w0, B2.w1, WbB + (size_t)126*JJ + 504 - 8*lane);
        aload2(B1.e0, B1.e1, EeB + (size_t)125*JJ + 504 - 8*lane); aload2(B1.w0, B1.w1, WbB + (size_t)125*JJ + 504 - 8*lane);
        aload2(B0.e0, B0.e1, EeB + (size_t)124*JJ + 504 - 8*lane); aload2(B0.w0, B0.w1, WbB + (size_t)124*JJ + 504 - 8*lane);
        bstep<true ,14,true>(126, lane, off, P3, P2, c, B2, B3, EeB, WbB, pbB, ldsC);
        bstep<false,16,true>(125, lane, off, P2, P1, c, B1, B2, EeB, WbB, pbB, ldsC);
        #pragma unroll 1
        for (int d = 0; d < 15; ++d) {        // steps 124..5
            int ib = 124 - 8 * d;
            bstep<false,18,true>(ib-0, lane, off, P1, P0, c, B0, B1, EeB, WbB, pbB, ldsC);
            bstep<false,18,true>(ib-1, lane, off, P0, P3, c, B3, B0, EeB, WbB, pbB, ldsC);
            bstep<true ,18,true>(ib-2, lane, off, P3, P2, c, B2, B3, EeB, WbB, pbB, ldsC);
            bstep<false,18,true>(ib-3, lane, off, P2, P1, c, B1, B2, EeB, WbB, pbB, ldsC);
            bstep<false,18,true>(ib-4, lane, off, P1, P0, c, B0, B1, EeB, WbB, pbB, ldsC);
            bstep<false,18,true>(ib-5, lane, off, P0, P3, c, B3, B0, EeB, WbB, pbB, ldsC);
            bstep<true ,18,true>(ib-6, lane, off, P3, P2, c, B2, B3, EeB, WbB, pbB, ldsC);
            bstep<false,18,true>(ib-7, lane, off, P2, P1, c, B1, B2, EeB, WbB, pbB, ldsC);
        }
        bstep<false,18,true >(4, lane, off, P1, P0, c, B0, B1, EeB, WbB, pbB, ldsC);
        bstep<false,18,true >(3, lane, off, P0, P3, c, B3, B0, EeB, WbB, pbB, ldsC);
        bstep<true ,14,false>(2, lane, off, P3, P2, c, B2, B3, EeB, WbB, pbB, ldsC);
        bstep<false,10,false>(1, lane, off, P2, P1, c, B1, B2, EeB, WbB, pbB, ldsC);
        bstep<false, 6,false>(0, lane, off, P1, P0, c, B0, B1, EeB, WbB, pbB, ldsC);
        storerow8(pbB + off, P0);           // row 0
        if (lane == 0) ldsC[0] = c;
        waitcnt_vm<0>();                    // drain our asm stores before endpgm
        cbB[lane]      = ldsC[lane];
        cbB[lane + 64] = ldsC[lane + 64];
    }
}

// ---------------- fused gamma + expand (unchanged) ----------------
__global__ __launch_bounds__(256) void gamma_expand_kernel(
        const float* __restrict__ pa, const float* __restrict__ pb,
        const float* __restrict__ ca, const float* __restrict__ cb,
        const float* __restrict__ text, const float* __restrict__ mmask,
        float* __restrict__ gamma_out, float* __restrict__ expanded) {
    __shared__ float wt[II][9];      // stride 9: phase-A writes ~2-way conflicts (free)
    __shared__ float Ei[II];
    __shared__ float red[8][33];     // partial column sums [q][ic]
    int b   = blockIdx.x >> 6;       // 64 tiles per batch
    int jj0 = (blockIdx.x & 63) * 8;
    int t = threadIdx.x;
    int q = t & 7, ic = t >> 3;      // ic 0..31 handles i = 4*ic..4*ic+3

    if (t < II) Ei[t] = ca[b*II + t] + cb[b*II + t];
    __syncthreads();
    float maxc = Ei[0];
    #pragma unroll 16
    for (int i = 1; i < II; ++i) maxc = fmaxf(maxc, Ei[i]);
    __syncthreads();
    if (t < II) Ei[t] = __expf(Ei[t] - maxc);
    __syncthreads();

    size_t idx0  = (size_t)b * II * JJ + jj0 + q;
    size_t idx0r = (size_t)b * II * JJ + (JJ - 1 - jj0 - q);   // pb stored j-reversed
    float d = 0.f;
    #pragma unroll
    for (int k = 0; k < 4; ++k) {
        int i = ic * 4 + k;
        float P = pa[idx0 + (size_t)i * JJ] * pb[idx0r + (size_t)i * JJ] * Ei[i];
        wt[i][q] = P;
        d += P;
    }
    red[q][ic] = d;
    __syncthreads();
    if (t < 8) {
        float s = 0.f;
        #pragma unroll
        for (int k = 0; k < 32; ++k) s += red[t][k];
        red[t][32] = 1.0f / fmaxf(s, 1e-37f);
    }
    __syncthreads();
    float rD = red[q][32];
    #pragma unroll
    for (int k = 0; k < 4; ++k) {
        int i = ic * 4 + k;
        float P = wt[i][q] * rD;
        wt[i][q] = P;
        gamma_out[idx0 + (size_t)i * JJ] = fmaxf(__logf(P), -1e30f);  // log(0)=-inf -> -1e30
    }
    __syncthreads();

    // phase B: expanded[b, jj0+qq, c=t] = mmask * sum_i wt[i][qq] * text[b,i,t]
    float acc[8] = {0,0,0,0,0,0,0,0};
    const float* txb = text + (size_t)b * II * CC + t;
    #pragma unroll 4
    for (int i = 0; i < II; ++i) {
        float tv = txb[(size_t)i * CC];
        #pragma unroll
        for (int qq = 0; qq < 8; ++qq) acc[qq] = fmaf(wt[i][qq], tv, acc[qq]);
    }
    #pragma unroll
    for (int qq = 0; qq < 8; ++qq) {
        expanded[(size_t)(b * JJ + jj0 + qq) * CC + t] =
            acc[qq] * mmask[b * JJ + jj0 + qq];
    }
}

extern "C" void kernel_launch(void* const* d_in, const int* in_sizes, int n_in,
                              void* d_out, int out_size, void* d_ws, size_t ws_size,
                              hipStream_t stream) {
    const float* text  = (const float*)d_in[0];
    const float* mel   = (const float*)d_in[1];
    const float* mmask = (const float*)d_in[3];
    const float* noise = (const float*)d_in[4];
    const float* ratio = (const float*)d_in[5];
    float* gamma_out = (float*)d_out;            // B*I*J floats
    float* expanded  = (float*)d_out + NEL;      // B*J*C floats

    float* ws = (float*)d_ws;
    float* Ee = ws;                  // NEL
    float* Wa = ws +   NEL;          // NEL
    float* Wb = ws + 2*NEL;          // NEL
    float* pa = ws + 3*NEL;          // NEL
    float* pb = ws + 4*NEL;          // NEL (j-reversed layout)
    float* ca = ws + 5*NEL;          // BB*II
    float* cb = ws + 5*NEL + BB*II;  // BB*II

    hipLaunchKernelGGL(energy_dscan_kernel, dim3(BB, II/8), dim3(256), 0, stream,
                       text, mel, noise, ratio, Ee, Wa, Wb);
    hipLaunchKernelGGL(scan_ab_kernel, dim3(BB*2), dim3(64), 0, stream,
                       Ee, Wa, Wb, pa, pb, ca, cb);
    hipLaunchKernelGGL(gamma_expand_kernel, dim3(BB*64), dim3(256), 0, stream,
                       pa, pb, ca, cb, text, mmask, gamma_out, expanded);
}

// Round 14
// 156.658 us; speedup vs baseline: 1.1222x; 1.1222x over previous
//
#include <hip/hip_runtime.h>
#include <math.h>

#define BB 2
#define II 128
#define JJ 512
#define CC 256
#define NEL (BB*II*JJ)   // 131072
#define NINF (-INFINITY)
#define K10 4.5399929762484854e-5f   // exp(-10)

typedef float f32x4 __attribute__((ext_vector_type(4)));

// ---------------- DPP wave64 primitives ----------------
template<int CTRL, int RM = 0xf, int BM = 0xf, bool BC = true>
__device__ __forceinline__ float dppf(float x) {
    return __int_as_float(__builtin_amdgcn_update_dpp(
        0, __float_as_int(x), CTRL, RM, BM, BC));
}
__device__ __forceinline__ float wscan_incl(float x) {
    x += dppf<0x111>(x);              // row_shr:1
    x += dppf<0x112>(x);              // row_shr:2
    x += dppf<0x114>(x);              // row_shr:4
    x += dppf<0x118>(x);              // row_shr:8
    x += dppf<0x142, 0xa>(x);         // row_bcast:15 -> rows 1,3
    x += dppf<0x143, 0xc>(x);         // row_bcast:31 -> rows 2,3
    return x;
}
__device__ __forceinline__ float lane_shr1(float x) { return dppf<0x138>(x); }  // wave_shr:1

// in-lane inclusive prefix sum, tree form (depth 3)
__device__ __forceinline__ void tree_prefix8(const float x[8], float P[8]) {
    float t[8];
    t[0] = x[0];
    #pragma unroll
    for (int q = 1; q < 8; ++q) t[q] = x[q] + x[q-1];
    float u[8];
    u[0] = t[0]; u[1] = t[1];
    #pragma unroll
    for (int q = 2; q < 8; ++q) u[q] = t[q] + t[q-2];
    P[0] = u[0]; P[1] = u[1]; P[2] = u[2]; P[3] = u[3];
    #pragma unroll
    for (int q = 4; q < 8; ++q) P[q] = u[q] + u[q-4];
}

__device__ __forceinline__ void loadrow8(const float* p, float v[8]) {
    float4 a = *reinterpret_cast<const float4*>(p);
    float4 b = *reinterpret_cast<const float4*>(p + 4);
    v[0]=a.x; v[1]=a.y; v[2]=a.z; v[3]=a.w;
    v[4]=b.x; v[5]=b.y; v[6]=b.z; v[7]=b.w;
}
__device__ __forceinline__ void storerow8(float* __restrict__ p, const float v[8]) {
    *reinterpret_cast<float4*>(p)     = make_float4(v[0],v[1],v[2],v[3]);
    *reinterpret_cast<float4*>(p + 4) = make_float4(v[4],v[5],v[6],v[7]);
}

// ---------------- hand-held vmem ops (invisible to SIInsertWaitcnts) ----------------
__device__ __forceinline__ void aload1(float &d, const float* p) {
    asm volatile("global_load_dword %0, %1, off" : "=&v"(d) : "v"(p) : "memory");
}
__device__ __forceinline__ void astore1(float d, float* p) {
    asm volatile("global_store_dword %1, %0, off" :: "v"(d), "v"(p) : "memory");
}
template<int N> __device__ __forceinline__ void waitcnt_vm() {
    asm volatile("s_waitcnt vmcnt(%0)" :: "i"(N) : "memory");
}
__device__ __forceinline__ void lgkm0_barrier() {
    asm volatile("s_waitcnt lgkmcnt(0)" ::: "memory");
    __builtin_amdgcn_s_barrier();
    __builtin_amdgcn_sched_barrier(0);
}

// ---------------- energy: tiled outer-product GEMM (R7 form) ----------------
__global__ __launch_bounds__(256) void energy_kernel(
        const float* __restrict__ text, const float* __restrict__ mel,
        const float* __restrict__ noise, const float* __restrict__ ratio,
        float* __restrict__ e) {
    __shared__ float melS[64][65];
    __shared__ float texS[8][65];
    int b  = blockIdx.x;
    int i0 = blockIdx.y * 8;
    int j0 = blockIdx.z * 64;
    int t = threadIdx.x;
    int jj = t & 63, ig = t >> 6;
    float acc0 = 0.f, acc1 = 0.f;
    for (int cc = 0; cc < CC; cc += 64) {
        #pragma unroll
        for (int k = 0; k < 4; ++k) {
            int idx = t + k * 256;
            int row = idx >> 4, seg = idx & 15;
            float4 v = *reinterpret_cast<const float4*>(
                mel + (size_t)(b * JJ + j0 + row) * CC + cc + seg * 4);
            melS[row][seg*4+0] = v.x; melS[row][seg*4+1] = v.y;
            melS[row][seg*4+2] = v.z; melS[row][seg*4+3] = v.w;
        }
        if (t < 128) {
            int row = t >> 4, seg = t & 15;
            float4 v = *reinterpret_cast<const float4*>(
                text + (size_t)(b * II + i0 + row) * CC + cc + seg * 4);
            texS[row][seg*4+0] = v.x; texS[row][seg*4+1] = v.y;
            texS[row][seg*4+2] = v.z; texS[row][seg*4+3] = v.w;
        }
        __syncthreads();
        #pragma unroll 8
        for (int c = 0; c < 64; ++c) {
            float m = melS[jj][c];
            acc0 = fmaf(m, texS[ig*2+0][c], acc0);
            acc1 = fmaf(m, texS[ig*2+1][c], acc1);
        }
        __syncthreads();
    }
    float temp = 0.1f + 0.9f * ratio[0];
    float rtmp = 1.0f / temp;
    int r0 = (b * II + i0 + ig*2 + 0) * JJ + j0 + jj;
    int r1 = (b * II + i0 + ig*2 + 1) * JJ + j0 + jj;
    e[r0] = (acc0 * (1.0f/256.0f) + noise[r0]) * rtmp;
    e[r1] = (acc1 * (1.0f/256.0f) + noise[r1]) * rtmp;
}

// ---------------- dscan (R7 form) ----------------
__global__ __launch_bounds__(64) void dscan_kernel(
        const float* __restrict__ e, float* __restrict__ Ee,
        float* __restrict__ Wa, float* __restrict__ Wb) {
    int row = blockIdx.x;
    int lane = threadIdx.x;
    float v[8];
    loadrow8(e + row * JJ + lane * 8, v);
    float m = v[0];
    #pragma unroll
    for (int q = 1; q < 8; ++q) m = fmaxf(m, v[q]);
    #pragma unroll
    for (int d = 1; d < 64; d <<= 1) m = fmaxf(m, __shfl_xor(m, d, 64));
    float x[8];
    #pragma unroll
    for (int q = 0; q < 8; ++q) x[q] = __expf(v[q] - m);
    storerow8(Ee + row * JJ + lane * 8, x);
    float run = 0.f, P[8];
    #pragma unroll
    for (int q = 0; q < 8; ++q) { run += x[q]; P[q] = run; }
    float sc = wscan_incl(run);
    float cp = lane_shr1(sc);
    float run2 = 0.f, S[8];
    #pragma unroll
    for (int q = 7; q >= 0; --q) { run2 += x[q]; S[q] = run2; }
    float sd = run2;
    #pragma unroll
    for (int d = 1; d < 64; d <<= 1) { float o = __shfl_down(sd, d, 64); sd += (lane + d < 64) ? o : 0.0f; }
    float cs = __shfl_down(sd, 1, 64); if (lane == 63) cs = 0.f;
    float wa[8], wb[8];
    #pragma unroll
    for (int q = 0; q < 8; ++q) {
        wa[q] = 1.0f / (S[q] + cs);
        wb[q] = 1.0f / (P[q] + cp);
    }
    storerow8(Wa + row * JJ + lane * 8, wa);
    storerow8(Wb + row * JJ + lane * 8, wb);
}

// ======================= scan_ab: 8-wave / 1-column-per-thread =======================
// All scan variants with 1 wave per (b,dir) share a per-wave outstanding-miss
// limit -> ~100us real (cold). This version: 512 threads, thread owns column j.
// Memory issued by 8 waves in parallel (8x line budget); full-row prefix =
// per-wave wscan + ONE barrier + 8 broadcast ds_read_b128 + chained offsets
// (lane-0 boundary term folded algebraically: tY_v = Yin_v + P_{v-1}*CW0_v).
// LDS totals double-buffered by step parity -> 1 barrier/step is race-free.
// vmem all inline asm, per-wave ledger: 3 ops/step [store][2 loads], d=8,
// warm vmcnt 15..21, steady 22, tail 22/20/18/16/14/12/10/8.

template<bool NORM, int VM, bool PF, int PTY>
__device__ __forceinline__ void astep8(int i, int t, int w, int lane,
    float pin, float &pout, float &c, float &Be, float &Bw,
    const float* __restrict__ EeB, const float* __restrict__ WaB,
    float* __restrict__ paB, f32x4 (*ldsX)[8], float* ldsC)
{
    astore1(pin, paB + (size_t)(i - 1) * JJ + t);     // pin holds row i-1
    if (t == 0) ldsC[i - 1] = c;
    waitcnt_vm<VM>();
    __builtin_amdgcn_sched_barrier(0);                // rule #18
    float CE = Be, CW = Bw;
    if (PF) { aload1(Be, EeB + (size_t)(i + 8) * JJ + t);
              aload1(Bw, WaB + (size_t)(i + 8) * JJ + t); }
    float zz   = (t == JJ - 1) ? 0.0f : pin;          // last row elem zeroed
    float y_in = lane_shr1(pin) * CW;                 // lane0 -> 0 (corrected below)
    float Yl_in = wscan_incl(y_in);
    float Zl    = wscan_incl(zz);
    float cw0 = __int_as_float(__builtin_amdgcn_readlane(__float_as_int(CW), 0));
    if (lane == 63) { f32x4 xv = {pin, Yl_in, Zl, cw0}; ldsX[PTY][w] = xv; }
    lgkm0_barrier();
    float offY = 0.f, offZ = 0.f, T = 0.f, prevP = 0.f, pupw = 0.f;
    #pragma unroll
    for (int v = 0; v < 8; ++v) {
        f32x4 xv = ldsX[PTY][v];
        float pup_v = prevP;                          // P of wave v-1 (0 for v=0)
        float tY = fmaf(pup_v, xv[3], xv[1]);         // wave-v y total incl lane0 corr
        float tZ = xv[2];
        if (v < w)  { offY += tY; offZ += tZ; }
        if (v == w) pupw = pup_v;
        T += tZ;
        prevP = xv[0];
    }
    float S1 = offY + Yl_in + pupw * cw0;             // incl prefix of y at j
    float S2 = fmaxf(T - (offZ + Zl) + zz, 0.0f);     // incl suffix of zz at j
    pout = fmaf(CE, S1, K10 * S2);
    if (NORM) {
        float Tc = fmaxf(T, 1e-30f);
        float rT = __builtin_amdgcn_rcpf(Tc);
        c += __logf(Tc);
        pout *= rT;
    }
}

template<bool NORM, int VM, bool PF, int PTY>
__device__ __forceinline__ void bstep8(int i, int t, int w, int lane,
    float pin, float &pout, float &c, float &Be, float &Bw,
    const float* __restrict__ EeB, const float* __restrict__ WbB,
    float* __restrict__ pbB, f32x4 (*ldsX)[8], float* ldsC)
{
    astore1(pin, pbB + (size_t)(i + 1) * JJ + t);     // pin holds row i+1
    if (t == 0) ldsC[i + 1] = c;
    waitcnt_vm<VM>();
    __builtin_amdgcn_sched_barrier(0);
    float CE = Be, CW = Bw;
    if (PF) { aload1(Be, EeB + (size_t)(i - 8) * JJ + (JJ - 1 - t));
              aload1(Bw, WbB + (size_t)(i - 8) * JJ + (JJ - 1 - t)); }
    float pn_in = lane_shr1(pin);                     // lane0 -> 0 (corrected below)
    float w_in  = pn_in * CW;
    float Wl_in = wscan_incl(w_in);
    float Nl_in = wscan_incl(pn_in);
    float cw0 = __int_as_float(__builtin_amdgcn_readlane(__float_as_int(CW), 0));
    if (lane == 63) { f32x4 xv = {pin, Wl_in, Nl_in, cw0}; ldsX[PTY][w] = xv; }
    lgkm0_barrier();
    float offW = 0.f, offN = 0.f, T = 0.f, prevP = 0.f, pupw = 0.f;
    #pragma unroll
    for (int v = 0; v < 8; ++v) {
        f32x4 xv = ldsX[PTY][v];
        float pup_v = prevP;
        float tW = fmaf(pup_v, xv[3], xv[1]);
        float tN = xv[2] + pup_v;
        if (v < w)  { offW += tW; offN += tN; }
        if (v == w) pupw = pup_v;
        T += tN;
        prevP = xv[0];
    }
    float QA = offW + Wl_in + pupw * cw0;             // incl prefix of w at j'
    float Nl = Nl_in + pupw;                          // incl prefix of pn at j'
    float QB = fmaxf(T - (offN + Nl), 0.0f);          // excl suffix of pn
    pout = fmaf(CE, QA, K10 * QB);
    if (NORM) {
        float Tc = fmaxf(T, 1e-30f);
        float rT = __builtin_amdgcn_rcpf(Tc);
        c += __logf(Tc);
        pout *= rT;
    }
}

__global__ __launch_bounds__(512, 1) void scan_ab_kernel(
        const float* __restrict__ Ee, const float* __restrict__ Wa,
        const float* __restrict__ Wb,
        float* __restrict__ pa, float* __restrict__ pb,
        float* __restrict__ ca, float* __restrict__ cb) {
    __shared__ f32x4 ldsX[2][8];
    __shared__ float ldsC[II];
    int b = blockIdx.x >> 1, dir = blockIdx.x & 1;
    int t = threadIdx.x;
    int w = t >> 6, lane = t & 63;
    size_t base = (size_t)b * II * JJ;
    float P0, P1, P2, P3, c = 0.0f;
    float S0e,S0w,S1e,S1w,S2e,S2w,S3e,S3w,S4e,S4w,S5e,S5w,S6e,S6w,S7e,S7w;

    if (dir == 0) {
        const float* EeB = Ee + base; const float* WaB = Wa + base;
        float* paB = pa + base; float* caB = ca + b * II;
        // row 0 via compiler loads (auto-waits land before the asm stream)
        float e0 = EeB[t];
        float wa00 = WaB[0];
        P0 = e0 * wa00;                                  // p row 0
        __builtin_amdgcn_sched_barrier(0);
        // asm prologue: rows 1..8 -> slots 1..7,0 (16 ops, order matters)
        aload1(S1e, EeB + (size_t)1*JJ + t); aload1(S1w, WaB + (size_t)1*JJ + t);
        aload1(S2e, EeB + (size_t)2*JJ + t); aload1(S2w, WaB + (size_t)2*JJ + t);
        aload1(S3e, EeB + (size_t)3*JJ + t); aload1(S3w, WaB + (size_t)3*JJ + t);
        aload1(S4e, EeB + (size_t)4*JJ + t); aload1(S4w, WaB + (size_t)4*JJ + t);
        aload1(S5e, EeB + (size_t)5*JJ + t); aload1(S5w, WaB + (size_t)5*JJ + t);
        aload1(S6e, EeB + (size_t)6*JJ + t); aload1(S6w, WaB + (size_t)6*JJ + t);
        aload1(S7e, EeB + (size_t)7*JJ + t); aload1(S7w, WaB + (size_t)7*JJ + t);
        aload1(S0e, EeB + (size_t)8*JJ + t); aload1(S0w, WaB + (size_t)8*JJ + t);
        // warm-up 1..7 (vmcnt 15..21)
        astep8<true ,15,true,1>(1, t,w,lane, P0, P1, c, S1e,S1w, EeB,WaB,paB, ldsX, ldsC);
        astep8<false,16,true,0>(2, t,w,lane, P1, P2, c, S2e,S2w, EeB,WaB,paB, ldsX, ldsC);
        astep8<false,17,true,1>(3, t,w,lane, P2, P3, c, S3e,S3w, EeB,WaB,paB, ldsX, ldsC);
        astep8<false,18,true,0>(4, t,w,lane, P3, P0, c, S4e,S4w, EeB,WaB,paB, ldsX, ldsC);
        astep8<true ,19,true,1>(5, t,w,lane, P0, P1, c, S5e,S5w, EeB,WaB,paB, ldsX, ldsC);
        astep8<false,20,true,0>(6, t,w,lane, P1, P2, c, S6e,S6w, EeB,WaB,paB, ldsX, ldsC);
        astep8<false,21,true,1>(7, t,w,lane, P2, P3, c, S7e,S7w, EeB,WaB,paB, ldsX, ldsC);
        #pragma unroll 1
        for (int d = 0; d < 14; ++d) {                   // steps 8..119
            int i = 8 + 8 * d;
            astep8<false,22,true,0>(i+0, t,w,lane, P3, P0, c, S0e,S0w, EeB,WaB,paB, ldsX, ldsC);
            astep8<true ,22,true,1>(i+1, t,w,lane, P0, P1, c, S1e,S1w, EeB,WaB,paB, ldsX, ldsC);
            astep8<false,22,true,0>(i+2, t,w,lane, P1, P2, c, S2e,S2w, EeB,WaB,paB, ldsX, ldsC);
            astep8<false,22,true,1>(i+3, t,w,lane, P2, P3, c, S3e,S3w, EeB,WaB,paB, ldsX, ldsC);
            astep8<false,22,true,0>(i+4, t,w,lane, P3, P0, c, S4e,S4w, EeB,WaB,paB, ldsX, ldsC);
            astep8<true ,22,true,1>(i+5, t,w,lane, P0, P1, c, S5e,S5w, EeB,WaB,paB, ldsX, ldsC);
            astep8<false,22,true,0>(i+6, t,w,lane, P1, P2, c, S6e,S6w, EeB,WaB,paB, ldsX, ldsC);
            astep8<false,22,true,1>(i+7, t,w,lane, P2, P3, c, S7e,S7w, EeB,WaB,paB, ldsX, ldsC);
        }
        // tail 120..127 (no PF)
        astep8<false,22,false,0>(120, t,w,lane, P3, P0, c, S0e,S0w, EeB,WaB,paB, ldsX, ldsC);
        astep8<true ,20,false,1>(121, t,w,lane, P0, P1, c, S1e,S1w, EeB,WaB,paB, ldsX, ldsC);
        astep8<false,18,false,0>(122, t,w,lane, P1, P2, c, S2e,S2w, EeB,WaB,paB, ldsX, ldsC);
        astep8<false,16,false,1>(123, t,w,lane, P2, P3, c, S3e,S3w, EeB,WaB,paB, ldsX, ldsC);
        astep8<false,14,false,0>(124, t,w,lane, P3, P0, c, S4e,S4w, EeB,WaB,paB, ldsX, ldsC);
        astep8<true ,12,false,1>(125, t,w,lane, P0, P1, c, S5e,S5w, EeB,WaB,paB, ldsX, ldsC);
        astep8<false,10,false,0>(126, t,w,lane, P1, P2, c, S6e,S6w, EeB,WaB,paB, ldsX, ldsC);
        astep8<false, 8,false,1>(127, t,w,lane, P2, P3, c, S7e,S7w, EeB,WaB,paB, ldsX, ldsC);
        astore1(P3, paB + (size_t)127 * JJ + t);
        if (t == 0) ldsC[127] = c;
        waitcnt_vm<0>();
        lgkm0_barrier();
        if (t < II) caB[t] = ldsC[t];
    } else {
        const float* EeB = Ee + base; const float* WbB = Wb + base;
        float* pbB = pb + base; float* cbB = cb + b * II;
        P0 = (t == 0) ? 1.0f : 0.0f;                     // p row 127 (reversed coords)
        __builtin_amdgcn_sched_barrier(0);
        // asm prologue: rows 126..119 -> slots 6,5,4,3,2,1,0,7 (reversed addressing)
        aload1(S6e, EeB + (size_t)126*JJ + (JJ-1-t)); aload1(S6w, WbB + (size_t)126*JJ + (JJ-1-t));
        aload1(S5e, EeB + (size_t)125*JJ + (JJ-1-t)); aload1(S5w, WbB + (size_t)125*JJ + (JJ-1-t));
        aload1(S4e, EeB + (size_t)124*JJ + (JJ-1-t)); aload1(S4w, WbB + (size_t)124*JJ + (JJ-1-t));
        aload1(S3e, EeB + (size_t)123*JJ + (JJ-1-t)); aload1(S3w, WbB + (size_t)123*JJ + (JJ-1-t));
        aload1(S2e, EeB + (size_t)122*JJ + (JJ-1-t)); aload1(S2w, WbB + (size_t)122*JJ + (JJ-1-t));
        aload1(S1e, EeB + (size_t)121*JJ + (JJ-1-t)); aload1(S1w, WbB + (size_t)121*JJ + (JJ-1-t));
        aload1(S0e, EeB + (size_t)120*JJ + (JJ-1-t)); aload1(S0w, WbB + (size_t)120*JJ + (JJ-1-t));
        aload1(S7e, EeB + (size_t)119*JJ + (JJ-1-t)); aload1(S7w, WbB + (size_t)119*JJ + (JJ-1-t));
        // warm-up 126..120 (vmcnt 15..21)
        bstep8<true ,15,true,0>(126, t,w,lane, P0, P1, c, S6e,S6w, EeB,WbB,pbB, ldsX, ldsC);
        bstep8<false,16,true,1>(125, t,w,lane, P1, P2, c, S5e,S5w, EeB,WbB,pbB, ldsX, ldsC);
        bstep8<false,17,true,0>(124, t,w,lane, P2, P3, c, S4e,S4w, EeB,WbB,pbB, ldsX, ldsC);
        bstep8<false,18,true,1>(123, t,w,lane, P3, P0, c, S3e,S3w, EeB,WbB,pbB, ldsX, ldsC);
        bstep8<true ,19,true,0>(122, t,w,lane, P0, P1, c, S2e,S2w, EeB,WbB,pbB, ldsX, ldsC);
        bstep8<false,20,true,1>(121, t,w,lane, P1, P2, c, S1e,S1w, EeB,WbB,pbB, ldsX, ldsC);
        bstep8<false,21,true,0>(120, t,w,lane, P2, P3, c, S0e,S0w, EeB,WbB,pbB, ldsX, ldsC);
        #pragma unroll 1
        for (int d = 0; d < 14; ++d) {                   // steps 119..8
            int i = 119 - 8 * d;
            bstep8<false,22,true,1>(i-0, t,w,lane, P3, P0, c, S7e,S7w, EeB,WbB,pbB, ldsX, ldsC);
            bstep8<true ,22,true,0>(i-1, t,w,lane, P0, P1, c, S6e,S6w, EeB,WbB,pbB, ldsX, ldsC);
            bstep8<false,22,true,1>(i-2, t,w,lane, P1, P2, c, S5e,S5w, EeB,WbB,pbB, ldsX, ldsC);
            bstep8<false,22,true,0>(i-3, t,w,lane, P2, P3, c, S4e,S4w, EeB,WbB,pbB, ldsX, ldsC);
            bstep8<false,22,true,1>(i-4, t,w,lane, P3, P0, c, S3e,S3w, EeB,WbB,pbB, ldsX, ldsC);
            bstep8<true ,22,true,0>(i-5, t,w,lane, P0, P1, c, S2e,S2w, EeB,WbB,pbB, ldsX, ldsC);
            bstep8<false,22,true,1>(i-6, t,w,lane, P1, P2, c, S1e,S1w, EeB,WbB,pbB, ldsX, ldsC);
            bstep8<false,22,true,0>(i-7, t,w,lane, P2, P3, c, S0e,S0w, EeB,WbB,pbB, ldsX, ldsC);
        }
        // tail 7..0 (no PF)
        bstep8<false,22,false,1>(7, t,w,lane, P3, P0, c, S7e,S7w, EeB,WbB,pbB, ldsX, ldsC);
        bstep8<true ,20,false,0>(6, t,w,lane, P0, P1, c, S6e,S6w, EeB,WbB,pbB, ldsX, ldsC);
        bstep8<false,18,false,1>(5, t,w,lane, P1, P2, c, S5e,S5w, EeB,WbB,pbB, ldsX, ldsC);
        bstep8<false,16,false,0>(4, t,w,lane, P2, P3, c, S4e,S4w, EeB,WbB,pbB, ldsX, ldsC);
        bstep8<false,14,false,1>(3, t,w,lane, P3, P0, c, S3e,S3w, EeB,WbB,pbB, ldsX, ldsC);
        bstep8<true ,12,false,0>(2, t,w,lane, P0, P1, c, S2e,S2w, EeB,WbB,pbB, ldsX, ldsC);
        bstep8<false,10,false,1>(1, t,w,lane, P1, P2, c, S1e,S1w, EeB,WbB,pbB, ldsX, ldsC);
        bstep8<false, 8,false,0>(0, t,w,lane, P2, P3, c, S0e,S0w, EeB,WbB,pbB, ldsX, ldsC);
        astore1(P3, pbB + t);                            // row 0 (reversed layout)
        if (t == 0) ldsC[0] = c;
        waitcnt_vm<0>();
        lgkm0_barrier();
        if (t < II) cbB[t] = ldsC[t];
    }
}

// ---------------- fused gamma + expand (R7 form) ----------------
__global__ __launch_bounds__(256) void gamma_expand_kernel(
        const float* __restrict__ pa, const float* __restrict__ pb,
        const float* __restrict__ ca, const float* __restrict__ cb,
        const float* __restrict__ text, const float* __restrict__ mmask,
        float* __restrict__ gamma_out, float* __restrict__ expanded) {
    __shared__ float wt[II][9];
    __shared__ float Ei[II];
    __shared__ float red[8][33];
    int b   = blockIdx.x >> 6;
    int jj0 = (blockIdx.x & 63) * 8;
    int t = threadIdx.x;
    int q = t & 7, ic = t >> 3;

    if (t < II) Ei[t] = ca[b*II + t] + cb[b*II + t];
    __syncthreads();
    float maxc = Ei[0];
    #pragma unroll 16
    for (int i = 1; i < II; ++i) maxc = fmaxf(maxc, Ei[i]);
    __syncthreads();
    if (t < II) Ei[t] = __expf(Ei[t] - maxc);
    __syncthreads();

    size_t idx0  = (size_t)b * II * JJ + jj0 + q;
    size_t idx0r = (size_t)b * II * JJ + (JJ - 1 - jj0 - q);   // pb stored j-reversed
    float d = 0.f;
    #pragma unroll
    for (int k = 0; k < 4; ++k) {
        int i = ic * 4 + k;
        float P = pa[idx0 + (size_t)i * JJ] * pb[idx0r + (size_t)i * JJ] * Ei[i];
        wt[i][q] = P;
        d += P;
    }
    red[q][ic] = d;
    __syncthreads();
    if (t < 8) {
        float s = 0.f;
        #pragma unroll
        for (int k = 0; k < 32; ++k) s += red[t][k];
        red[t][32] = 1.0f / fmaxf(s, 1e-37f);
    }
    __syncthreads();
    float rD = red[q][32];
    #pragma unroll
    for (int k = 0; k < 4; ++k) {
        int i = ic * 4 + k;
        float P = wt[i][q] * rD;
        wt[i][q] = P;
        gamma_out[idx0 + (size_t)i * JJ] = fmaxf(__logf(P), -1e30f);
    }
    __syncthreads();

    float acc[8] = {0,0,0,0,0,0,0,0};
    const float* txb = text + (size_t)b * II * CC + t;
    #pragma unroll 4
    for (int i = 0; i < II; ++i) {
        float tv = txb[(size_t)i * CC];
        #pragma unroll
        for (int qq = 0; qq < 8; ++qq) acc[qq] = fmaf(wt[i][qq], tv, acc[qq]);
    }
    #pragma unroll
    for (int qq = 0; qq < 8; ++qq) {
        expanded[(size_t)(b * JJ + jj0 + qq) * CC + t] =
            acc[qq] * mmask[b * JJ + jj0 + qq];
    }
}

extern "C" void kernel_launch(void* const* d_in, const int* in_sizes, int n_in,
                              void* d_out, int out_size, void* d_ws, size_t ws_size,
                              hipStream_t stream) {
    const float* text  = (const float*)d_in[0];
    const float* mel   = (const float*)d_in[1];
    const float* mmask = (const float*)d_in[3];
    const float* noise = (const float*)d_in[4];
    const float* ratio = (const float*)d_in[5];
    float* gamma_out = (float*)d_out;            // B*I*J floats
    float* expanded  = (float*)d_out + NEL;      // B*J*C floats

    float* ws = (float*)d_ws;
    float* Ee = ws;                  // NEL
    float* Wa = ws +   NEL;          // NEL
    float* Wb = ws + 2*NEL;          // NEL
    float* pa = ws + 3*NEL;          // NEL (aliased: e lives here pre-scan)
    float* pb = ws + 4*NEL;          // NEL (j-reversed layout)
    float* ca = ws + 5*NEL;          // BB*II
    float* cb = ws + 5*NEL + BB*II;  // BB*II
    float* e  = pa;                  // e dead once scan_ab starts writing pa

    hipLaunchKernelGGL(energy_kernel, dim3(BB, II/8, JJ/64), dim3(256), 0, stream,
                       text, mel, noise, ratio, e);
    hipLaunchKernelGGL(dscan_kernel, dim3(BB*II), dim3(64), 0, stream, e, Ee, Wa, Wb);
    hipLaunchKernelGGL(scan_ab_kernel, dim3(BB*2), dim3(512), 0, stream,
                       Ee, Wa, Wb, pa, pb, ca, cb);
    hipLaunchKernelGGL(gamma_expand_kernel, dim3(BB*64), dim3(256), 0, stream,
                       pa, pb, ca, cb, text, mmask, gamma_out, expanded);
}

// Round 15
// 155.816 us; speedup vs baseline: 1.1283x; 1.0054x over previous
//
#include <hip/hip_runtime.h>
#include <math.h>

#define BB 2
#define II 128
#define JJ 512
#define CC 256
#define NEL (BB*II*JJ)   // 131072
#define NINF (-INFINITY)
#define K10 4.5399929762484854e-5f   // exp(-10)
#define RING 12

typedef float f32x4 __attribute__((ext_vector_type(4)));

// ---------------- DPP wave64 primitives ----------------
template<int CTRL, int RM = 0xf, int BM = 0xf, bool BC = true>
__device__ __forceinline__ float dppf(float x) {
    return __int_as_float(__builtin_amdgcn_update_dpp(
        0, __float_as_int(x), CTRL, RM, BM, BC));
}
__device__ __forceinline__ float wscan_incl(float x) {
    x += dppf<0x111>(x);              // row_shr:1
    x += dppf<0x112>(x);              // row_shr:2
    x += dppf<0x114>(x);              // row_shr:4
    x += dppf<0x118>(x);              // row_shr:8
    x += dppf<0x142, 0xa>(x);         // row_bcast:15 -> rows 1,3
    x += dppf<0x143, 0xc>(x);         // row_bcast:31 -> rows 2,3
    return x;
}
__device__ __forceinline__ float lane_shr1(float x) { return dppf<0x138>(x); }
__device__ __forceinline__ float bcast63(float x) {
    return __int_as_float(__builtin_amdgcn_readlane(__float_as_int(x), 63));
}

// in-lane inclusive prefix sum, tree form (depth 3)
__device__ __forceinline__ void tree_prefix8(const float x[8], float P[8]) {
    float t[8];
    t[0] = x[0];
    #pragma unroll
    for (int q = 1; q < 8; ++q) t[q] = x[q] + x[q-1];
    float u[8];
    u[0] = t[0]; u[1] = t[1];
    #pragma unroll
    for (int q = 2; q < 8; ++q) u[q] = t[q] + t[q-2];
    P[0] = u[0]; P[1] = u[1]; P[2] = u[2]; P[3] = u[3];
    #pragma unroll
    for (int q = 4; q < 8; ++q) P[q] = u[q] + u[q-4];
}

__device__ __forceinline__ void loadrow8(const float* p, float v[8]) {
    float4 a = *reinterpret_cast<const float4*>(p);
    float4 b = *reinterpret_cast<const float4*>(p + 4);
    v[0]=a.x; v[1]=a.y; v[2]=a.z; v[3]=a.w;
    v[4]=b.x; v[5]=b.y; v[6]=b.z; v[7]=b.w;
}
__device__ __forceinline__ void storerow8(float* __restrict__ p, const float v[8]) {
    *reinterpret_cast<float4*>(p)     = make_float4(v[0],v[1],v[2],v[3]);
    *reinterpret_cast<float4*>(p + 4) = make_float4(v[4],v[5],v[6],v[7]);
}

// ---------------- hand-held vmem ops (invisible to SIInsertWaitcnts) ----------------
__device__ __forceinline__ void astore2(f32x4 d0, f32x4 d1, float* p) {
    asm volatile("global_store_dwordx4 %2, %0, off\n\t"
                 "global_store_dwordx4 %2, %1, off offset:16"
                 :: "v"(d0), "v"(d1), "v"(p) : "memory");
}
template<int N> __device__ __forceinline__ void waitcnt_vm() {
    asm volatile("s_waitcnt vmcnt(%0)" :: "i"(N) : "memory");
}
// async global->LDS DMA (per-wave vmcnt; lane i writes LDS base + i*16B)
typedef __attribute__((address_space(1))) float gfloat;
typedef __attribute__((address_space(3))) float lfloat;
__device__ __forceinline__ void gl_lds16(const float* g, float* l) {
    __builtin_amdgcn_global_load_lds((gfloat*)g, (lfloat*)l, 16, 0, 0);
}

// ---------------- energy: tiled outer-product GEMM (R7 form) ----------------
__global__ __launch_bounds__(256) void energy_kernel(
        const float* __restrict__ text, const float* __restrict__ mel,
        const float* __restrict__ noise, const float* __restrict__ ratio,
        float* __restrict__ e) {
    __shared__ float melS[64][65];
    __shared__ float texS[8][65];
    int b  = blockIdx.x;
    int i0 = blockIdx.y * 8;
    int j0 = blockIdx.z * 64;
    int t = threadIdx.x;
    int jj = t & 63, ig = t >> 6;
    float acc0 = 0.f, acc1 = 0.f;
    for (int cc = 0; cc < CC; cc += 64) {
        #pragma unroll
        for (int k = 0; k < 4; ++k) {
            int idx = t + k * 256;
            int row = idx >> 4, seg = idx & 15;
            float4 v = *reinterpret_cast<const float4*>(
                mel + (size_t)(b * JJ + j0 + row) * CC + cc + seg * 4);
            melS[row][seg*4+0] = v.x; melS[row][seg*4+1] = v.y;
            melS[row][seg*4+2] = v.z; melS[row][seg*4+3] = v.w;
        }
        if (t < 128) {
            int row = t >> 4, seg = t & 15;
            float4 v = *reinterpret_cast<const float4*>(
                text + (size_t)(b * II + i0 + row) * CC + cc + seg * 4);
            texS[row][seg*4+0] = v.x; texS[row][seg*4+1] = v.y;
            texS[row][seg*4+2] = v.z; texS[row][seg*4+3] = v.w;
        }
        __syncthreads();
        #pragma unroll 8
        for (int c = 0; c < 64; ++c) {
            float m = melS[jj][c];
            acc0 = fmaf(m, texS[ig*2+0][c], acc0);
            acc1 = fmaf(m, texS[ig*2+1][c], acc1);
        }
        __syncthreads();
    }
    float temp = 0.1f + 0.9f * ratio[0];
    float rtmp = 1.0f / temp;
    int r0 = (b * II + i0 + ig*2 + 0) * JJ + j0 + jj;
    int r1 = (b * II + i0 + ig*2 + 1) * JJ + j0 + jj;
    e[r0] = (acc0 * (1.0f/256.0f) + noise[r0]) * rtmp;
    e[r1] = (acc1 * (1.0f/256.0f) + noise[r1]) * rtmp;
}

// ---------------- dscan (R7 form) ----------------
__global__ __launch_bounds__(64) void dscan_kernel(
        const float* __restrict__ e, float* __restrict__ Ee,
        float* __restrict__ Wa, float* __restrict__ Wb) {
    int row = blockIdx.x;
    int lane = threadIdx.x;
    float v[8];
    loadrow8(e + row * JJ + lane * 8, v);
    float m = v[0];
    #pragma unroll
    for (int q = 1; q < 8; ++q) m = fmaxf(m, v[q]);
    #pragma unroll
    for (int d = 1; d < 64; d <<= 1) m = fmaxf(m, __shfl_xor(m, d, 64));
    float x[8];
    #pragma unroll
    for (int q = 0; q < 8; ++q) x[q] = __expf(v[q] - m);
    storerow8(Ee + row * JJ + lane * 8, x);
    float run = 0.f, P[8];
    #pragma unroll
    for (int q = 0; q < 8; ++q) { run += x[q]; P[q] = run; }
    float sc = wscan_incl(run);
    float cp = lane_shr1(sc);
    float run2 = 0.f, S[8];
    #pragma unroll
    for (int q = 7; q >= 0; --q) { run2 += x[q]; S[q] = run2; }
    float sd = run2;
    #pragma unroll
    for (int d = 1; d < 64; d <<= 1) { float o = __shfl_down(sd, d, 64); sd += (lane + d < 64) ? o : 0.0f; }
    float cs = __shfl_down(sd, 1, 64); if (lane == 63) cs = 0.f;
    float wa[8], wb[8];
    #pragma unroll
    for (int q = 0; q < 8; ++q) {
        wa[q] = 1.0f / (S[q] + cs);
        wb[q] = 1.0f / (P[q] + cp);
    }
    storerow8(Wa + row * JJ + lane * 8, wa);
    storerow8(Wb + row * JJ + lane * 8, wb);
}

// ======================= scan_ab: producer/consumer wave specialization =======================
// Cold-run binder (R6-R9,R14 evidence): remote-L2/L3 load latency x ONE wave's
// in-order vmcnt queue (collapses >32 outstanding), ~95-100us timed regardless
// of prefetch scheduling; barriers (R14) couple waves and make it worse.
// Fix: per-wave vmcnt counters. 4 producer waves DMA rows into a 12-slot LDS
// ring (4 x global_load_lds -> own vmcnt(0) -> volatile flag). Consumer wave
// runs the R7 recursion with NO loads (data from LDS); its vmem queue = 2
// stores/step; P-ring depth 8 + vmcnt(14) => store-ack pacing ack/7.
// Handshake: flag[s]==k when row k resident; done = last consumed index;
// producer of row k waits done >= k-RING. No barriers after init.

template<bool NORM>
__device__ __forceinline__ void astepL(
    int i, int lane, int off,
    const float (&pin)[8], float (&pout)[8], float& c,
    float (*ringE)[JJ], float (*ringW)[JJ],
    volatile int* vflg, volatile int* vdone,
    float* __restrict__ paB, float* ldsC)
{
    {
        f32x4 s0 = {pin[0], pin[1], pin[2], pin[3]};
        f32x4 s1 = {pin[4], pin[5], pin[6], pin[7]};
        astore2(s0, s1, paB + (size_t)(i - 1) * JJ + off);   // pin holds row i-1
    }
    if (lane == 0) { ldsC[i - 1] = c; *vdone = i - 1; }
    int s = i % RING;
    while (vflg[s] != i) __builtin_amdgcn_s_sleep(1);
    waitcnt_vm<14>();                       // stores 7 steps old acked (P-ring 8)
    __builtin_amdgcn_sched_barrier(0);      // rule #18
    float CE[8], CW[8];
    loadrow8(&ringE[s][off], CE);
    loadrow8(&ringW[s][off], CW);

    float pup = lane_shr1(pin[7]);
    float y[8];
    y[0] = pup * CW[0];
    #pragma unroll
    for (int q = 1; q < 8; ++q) y[q] = pin[q-1] * CW[q];
    float zz[8];
    #pragma unroll
    for (int q = 0; q < 7; ++q) zz[q] = pin[q];
    zz[7] = (lane == 63) ? 0.0f : pin[7];
    float Y[8], Z[8];
    tree_prefix8(y, Y);
    tree_prefix8(zz, Z);
    float sy = wscan_incl(Y[7]);
    float sz = wscan_incl(Z[7]);
    float oy = lane_shr1(sy);
    float oz = lane_shr1(sz);
    float T  = bcast63(sz);
    #pragma unroll
    for (int q = 0; q < 8; ++q) {
        float S1 = oy + Y[q];                              // incl prefix of y
        float S2 = fmaxf(T - (oz + Z[q]) + zz[q], 0.0f);   // incl suffix of z
        pout[q] = fmaf(CE[q], S1, K10 * S2);
    }
    if (NORM) {
        float Tc = fmaxf(T, 1e-30f);
        float rT = __builtin_amdgcn_rcpf(Tc);
        c += __logf(Tc);
        #pragma unroll
        for (int q = 0; q < 8; ++q) pout[q] *= rT;
    }
}

template<bool NORM>
__device__ __forceinline__ void bstepL(
    int i, int lane, int off,
    const float (&pin)[8], float (&pout)[8], float& c,
    float (*ringE)[JJ], float (*ringW)[JJ],
    volatile int* vflg, volatile int* vdone,
    float* __restrict__ pbB, float* ldsC)
{
    {
        f32x4 s0 = {pin[0], pin[1], pin[2], pin[3]};
        f32x4 s1 = {pin[4], pin[5], pin[6], pin[7]};
        astore2(s0, s1, pbB + (size_t)(i + 1) * JJ + off);   // pin holds row i+1
    }
    int q126 = 126 - i;                     // sequence index
    if (lane == 0) { ldsC[i + 1] = c; *vdone = q126 - 1; }
    int s = q126 % RING;
    while (vflg[s] != q126) __builtin_amdgcn_s_sleep(1);
    waitcnt_vm<14>();
    __builtin_amdgcn_sched_barrier(0);
    float tE[8], tW[8], CE[8], CW[8];
    loadrow8(&ringE[s][504 - off], tE);     // reversed: CE[q] = row[511-8*lane-q]
    loadrow8(&ringW[s][504 - off], tW);
    #pragma unroll
    for (int q = 0; q < 8; ++q) { CE[q] = tE[7-q]; CW[q] = tW[7-q]; }

    float pup = lane_shr1(pin[7]);
    float pn[8];
    pn[0] = pup;
    #pragma unroll
    for (int q = 1; q < 8; ++q) pn[q] = pin[q-1];
    float w[8];
    #pragma unroll
    for (int q = 0; q < 8; ++q) w[q] = pn[q] * CW[q];
    float W[8], N[8];
    tree_prefix8(w, W);
    tree_prefix8(pn, N);
    float sw = wscan_incl(W[7]);
    float sn = wscan_incl(N[7]);
    float ow = lane_shr1(sw);
    float on = lane_shr1(sn);
    float T  = bcast63(sn);
    #pragma unroll
    for (int q = 0; q < 8; ++q) {
        float QA = ow + W[q];                    // incl prefix of w
        float QB = fmaxf(T - (on + N[q]), 0.0f); // excl suffix of pn
        pout[q] = fmaf(CE[q], QA, K10 * QB);
    }
    if (NORM) {
        float Tc = fmaxf(T, 1e-30f);
        float rT = __builtin_amdgcn_rcpf(Tc);
        c += __logf(Tc);
        #pragma unroll
        for (int q = 0; q < 8; ++q) pout[q] *= rT;
    }
}

__global__ __launch_bounds__(320, 1) void scan_ab_kernel(
        const float* __restrict__ Ee, const float* __restrict__ Wa,
        const float* __restrict__ Wb,
        float* __restrict__ pa, float* __restrict__ pb,
        float* __restrict__ ca, float* __restrict__ cb) {
    __shared__ float ringE[RING][JJ];
    __shared__ float ringW[RING][JJ];
    __shared__ int   flg[RING];
    __shared__ int   done;
    __shared__ float ldsC[II];
    int b = blockIdx.x >> 1, dir = blockIdx.x & 1;
    int t = threadIdx.x;
    int lane = t & 63, w = t >> 6;
    size_t base = (size_t)b * II * JJ;
    const float* EeB = Ee + base;
    const float* WB  = (dir == 0 ? Wa : Wb) + base;
    volatile int* vflg  = flg;
    volatile int* vdone = &done;

    if (t < RING) flg[t] = -1;
    if (t == RING) done = -1;
    __syncthreads();    // the ONLY barrier

    if (w >= 1) {
        // -------- producer waves 1..4: own vmcnt queues --------
        int nk = (dir == 0) ? 128 : 127;
        for (int k = w - 1; k < nk; k += 4) {
            int s = k % RING;
            if (k >= RING) {
                while (*vdone < k - RING) __builtin_amdgcn_s_sleep(2);
            }
            int row = (dir == 0) ? k : (126 - k);
            const float* gE = EeB + (size_t)row * JJ;
            const float* gW = WB  + (size_t)row * JJ;
            gl_lds16(gE + lane * 4,       &ringE[s][0]);
            gl_lds16(gE + 256 + lane * 4, &ringE[s][256]);
            gl_lds16(gW + lane * 4,       &ringW[s][0]);
            gl_lds16(gW + 256 + lane * 4, &ringW[s][256]);
            waitcnt_vm<0>();              // row resident in LDS
            if (lane == 0) vflg[s] = k;
        }
        return;
    }

    // -------- consumer wave 0 --------
    int off = lane * 8;
    float P0[8],P1[8],P2[8],P3[8],P4[8],P5[8],P6[8],P7[8], c = 0.0f;

    if (dir == 0) {
        float* paB = pa + base; float* caB = ca + b * II;
        while (vflg[0] != 0) __builtin_amdgcn_s_sleep(1);
        float e0r[8];
        loadrow8(&ringE[0][off], e0r);
        float wa00 = ringW[0][0];
        #pragma unroll
        for (int q = 0; q < 8; ++q) P0[q] = e0r[q] * wa00;   // row 0
        // steps 1..7
        astepL<true >(1, lane, off, P0, P1, c, ringE, ringW, vflg, vdone, paB, ldsC);
        astepL<false>(2, lane, off, P1, P2, c, ringE, ringW, vflg, vdone, paB, ldsC);
        astepL<false>(3, lane, off, P2, P3, c, ringE, ringW, vflg, vdone, paB, ldsC);
        astepL<false>(4, lane, off, P3, P4, c, ringE, ringW, vflg, vdone, paB, ldsC);
        astepL<true >(5, lane, off, P4, P5, c, ringE, ringW, vflg, vdone, paB, ldsC);
        astepL<false>(6, lane, off, P5, P6, c, ringE, ringW, vflg, vdone, paB, ldsC);
        astepL<false>(7, lane, off, P6, P7, c, ringE, ringW, vflg, vdone, paB, ldsC);
        #pragma unroll 1
        for (int d = 0; d < 14; ++d) {        // steps 8..119
            int i = 8 + 8 * d;
            astepL<false>(i+0, lane, off, P7, P0, c, ringE, ringW, vflg, vdone, paB, ldsC);
            astepL<true >(i+1, lane, off, P0, P1, c, ringE, ringW, vflg, vdone, paB, ldsC);
            astepL<false>(i+2, lane, off, P1, P2, c, ringE, ringW, vflg, vdone, paB, ldsC);
            astepL<false>(i+3, lane, off, P2, P3, c, ringE, ringW, vflg, vdone, paB, ldsC);
            astepL<false>(i+4, lane, off, P3, P4, c, ringE, ringW, vflg, vdone, paB, ldsC);
            astepL<true >(i+5, lane, off, P4, P5, c, ringE, ringW, vflg, vdone, paB, ldsC);
            astepL<false>(i+6, lane, off, P5, P6, c, ringE, ringW, vflg, vdone, paB, ldsC);
            astepL<false>(i+7, lane, off, P6, P7, c, ringE, ringW, vflg, vdone, paB, ldsC);
        }
        // steps 120..127
        astepL<false>(120, lane, off, P7, P0, c, ringE, ringW, vflg, vdone, paB, ldsC);
        astepL<true >(121, lane, off, P0, P1, c, ringE, ringW, vflg, vdone, paB, ldsC);
        astepL<false>(122, lane, off, P1, P2, c, ringE, ringW, vflg, vdone, paB, ldsC);
        astepL<false>(123, lane, off, P2, P3, c, ringE, ringW, vflg, vdone, paB, ldsC);
        astepL<false>(124, lane, off, P3, P4, c, ringE, ringW, vflg, vdone, paB, ldsC);
        astepL<true >(125, lane, off, P4, P5, c, ringE, ringW, vflg, vdone, paB, ldsC);
        astepL<false>(126, lane, off, P5, P6, c, ringE, ringW, vflg, vdone, paB, ldsC);
        astepL<false>(127, lane, off, P6, P7, c, ringE, ringW, vflg, vdone, paB, ldsC);
        storerow8(paB + (size_t)127 * JJ + off, P7);
        if (lane == 0) ldsC[127] = c;
        waitcnt_vm<0>();                       // drain asm stores before endpgm
        caB[lane]      = ldsC[lane];
        caB[lane + 64] = ldsC[lane + 64];
    } else {
        float* pbB = pb + base; float* cbB = cb + b * II;
        #pragma unroll
        for (int q = 0; q < 8; ++q) P0[q] = 0.0f;
        P0[0] = (lane == 0) ? 1.0f : 0.0f;   // row 127 (j'=0 <-> orig j=J-1)
        // steps 126..120
        bstepL<true >(126, lane, off, P0, P1, c, ringE, ringW, vflg, vdone, pbB, ldsC);
        bstepL<false>(125, lane, off, P1, P2, c, ringE, ringW, vflg, vdone, pbB, ldsC);
        bstepL<false>(124, lane, off, P2, P3, c, ringE, ringW, vflg, vdone, pbB, ldsC);
        bstepL<false>(123, lane, off, P3, P4, c, ringE, ringW, vflg, vdone, pbB, ldsC);
        bstepL<true >(122, lane, off, P4, P5, c, ringE, ringW, vflg, vdone, pbB, ldsC);
        bstepL<false>(121, lane, off, P5, P6, c, ringE, ringW, vflg, vdone, pbB, ldsC);
        bstepL<false>(120, lane, off, P6, P7, c, ringE, ringW, vflg, vdone, pbB, ldsC);
        #pragma unroll 1
        for (int d = 0; d < 14; ++d) {        // steps 119..8
            int i = 119 - 8 * d;
            bstepL<false>(i-0, lane, off, P7, P0, c, ringE, ringW, vflg, vdone, pbB, ldsC);
            bstepL<true >(i-1, lane, off, P0, P1, c, ringE, ringW, vflg, vdone, pbB, ldsC);
            bstepL<false>(i-2, lane, off, P1, P2, c, ringE, ringW, vflg, vdone, pbB, ldsC);
            bstepL<false>(i-3, lane, off, P2, P3, c, ringE, ringW, vflg, vdone, pbB, ldsC);
            bstepL<false>(i-4, lane, off, P3, P4, c, ringE, ringW, vflg, vdone, pbB, ldsC);
            bstepL<true >(i-5, lane, off, P4, P5, c, ringE, ringW, vflg, vdone, pbB, ldsC);
            bstepL<false>(i-6, lane, off, P5, P6, c, ringE, ringW, vflg, vdone, pbB, ldsC);
            bstepL<false>(i-7, lane, off, P6, P7, c, ringE, ringW, vflg, vdone, pbB, ldsC);
        }
        // steps 7..0
        bstepL<false>(7, lane, off, P7, P0, c, ringE, ringW, vflg, vdone, pbB, ldsC);
        bstepL<true >(6, lane, off, P0, P1, c, ringE, ringW, vflg, vdone, pbB, ldsC);
        bstepL<false>(5, lane, off, P1, P2, c, ringE, ringW, vflg, vdone, pbB, ldsC);
        bstepL<false>(4, lane, off, P2, P3, c, ringE, ringW, vflg, vdone, pbB, ldsC);
        bstepL<false>(3, lane, off, P3, P4, c, ringE, ringW, vflg, vdone, pbB, ldsC);
        bstepL<true >(2, lane, off, P4, P5, c, ringE, ringW, vflg, vdone, pbB, ldsC);
        bstepL<false>(1, lane, off, P5, P6, c, ringE, ringW, vflg, vdone, pbB, ldsC);
        bstepL<false>(0, lane, off, P6, P7, c, ringE, ringW, vflg, vdone, pbB, ldsC);
        storerow8(pbB + off, P7);           // row 0 (reversed layout)
        if (lane == 0) ldsC[0] = c;
        waitcnt_vm<0>();
        cbB[lane]      = ldsC[lane];
        cbB[lane + 64] = ldsC[lane + 64];
    }
}

// ---------------- fused gamma + expand (R7 form) ----------------
__global__ __launch_bounds__(256) void gamma_expand_kernel(
        const float* __restrict__ pa, const float* __restrict__ pb,
        const float* __restrict__ ca, const float* __restrict__ cb,
        const float* __restrict__ text, const float* __restrict__ mmask,
        float* __restrict__ gamma_out, float* __restrict__ expanded) {
    __shared__ float wt[II][9];
    __shared__ float Ei[II];
    __shared__ float red[8][33];
    int b   = blockIdx.x >> 6;
    int jj0 = (blockIdx.x & 63) * 8;
    int t = threadIdx.x;
    int q = t & 7, ic = t >> 3;

    if (t < II) Ei[t] = ca[b*II + t] + cb[b*II + t];
    __syncthreads();
    float maxc = Ei[0];
    #pragma unroll 16
    for (int i = 1; i < II; ++i) maxc = fmaxf(maxc, Ei[i]);
    __syncthreads();
    if (t < II) Ei[t] = __expf(Ei[t] - maxc);
    __syncthreads();

    size_t idx0  = (size_t)b * II * JJ + jj0 + q;
    size_t idx0r = (size_t)b * II * JJ + (JJ - 1 - jj0 - q);   // pb stored j-reversed
    float d = 0.f;
    #pragma unroll
    for (int k = 0; k < 4; ++k) {
        int i = ic * 4 + k;
        float P = pa[idx0 + (size_t)i * JJ] * pb[idx0r + (size_t)i * JJ] * Ei[i];
        wt[i][q] = P;
        d += P;
    }
    red[q][ic] = d;
    __syncthreads();
    if (t < 8) {
        float s = 0.f;
        #pragma unroll
        for (int k = 0; k < 32; ++k) s += red[t][k];
        red[t][32] = 1.0f / fmaxf(s, 1e-37f);
    }
    __syncthreads();
    float rD = red[q][32];
    #pragma unroll
    for (int k = 0; k < 4; ++k) {
        int i = ic * 4 + k;
        float P = wt[i][q] * rD;
        wt[i][q] = P;
        gamma_out[idx0 + (size_t)i * JJ] = fmaxf(__logf(P), -1e30f);
    }
    __syncthreads();

    float acc[8] = {0,0,0,0,0,0,0,0};
    const float* txb = text + (size_t)b * II * CC + t;
    #pragma unroll 4
    for (int i = 0; i < II; ++i) {
        float tv = txb[(size_t)i * CC];
        #pragma unroll
        for (int qq = 0; qq < 8; ++qq) acc[qq] = fmaf(wt[i][qq], tv, acc[qq]);
    }
    #pragma unroll
    for (int qq = 0; qq < 8; ++qq) {
        expanded[(size_t)(b * JJ + jj0 + qq) * CC + t] =
            acc[qq] * mmask[b * JJ + jj0 + qq];
    }
}

extern "C" void kernel_launch(void* const* d_in, const int* in_sizes, int n_in,
                              void* d_out, int out_size, void* d_ws, size_t ws_size,
                              hipStream_t stream) {
    const float* text  = (const float*)d_in[0];
    const float* mel   = (const float*)d_in[1];
    const float* mmask = (const float*)d_in[3];
    const float* noise = (const float*)d_in[4];
    const float* ratio = (const float*)d_in[5];
    float* gamma_out = (float*)d_out;            // B*I*J floats
    float* expanded  = (float*)d_out + NEL;      // B*J*C floats

    float* ws = (float*)d_ws;
    float* Ee = ws;                  // NEL
    float* Wa = ws +   NEL;          // NEL
    float* Wb = ws + 2*NEL;          // NEL
    float* pa = ws + 3*NEL;          // NEL (aliased: e lives here pre-scan)
    float* pb = ws + 4*NEL;          // NEL (j-reversed layout)
    float* ca = ws + 5*NEL;          // BB*II
    float* cb = ws + 5*NEL + BB*II;  // BB*II
    float* e  = pa;                  // e dead once scan_ab starts writing pa

    hipLaunchKernelGGL(energy_kernel, dim3(BB, II/8, JJ/64), dim3(256), 0, stream,
                       text, mel, noise, ratio, e);
    hipLaunchKernelGGL(dscan_kernel, dim3(BB*II), dim3(64), 0, stream, e, Ee, Wa, Wb);
    hipLaunchKernelGGL(scan_ab_kernel, dim3(BB*2), dim3(320), 0, stream,
                       Ee, Wa, Wb, pa, pb, ca, cb);
    hipLaunchKernelGGL(gamma_expand_kernel, dim3(BB*64), dim3(256), 0, stream,
                       pa, pb, ca, cb, text, mmask, gamma_out, expanded);
}